// Round 6
// baseline (4402.144 us; speedup 1.0000x reference)
//
#include <hip/hip_runtime.h>
#include <cstdint>
#include <cstddef>

#define NEGV -1000000000.0f

// ---------- fast device math (fp32, argmax-safe) ----------
__device__ __forceinline__ float fsigm(float x) { return 1.0f / (1.0f + __expf(-x)); }
__device__ __forceinline__ float ftanh(float x) {
  x = fminf(x, 30.0f);
  const float e = __expf(2.0f * x);
  return (e - 1.0f) / (e + 1.0f);
}

// ---------------------------------------------------------------------------
// prep1: weight repacks (no intra-launch deps).  (unchanged from round 5)
// ---------------------------------------------------------------------------
__global__ __launch_bounds__(256) void prep1_k(
    const float* __restrict__ Wih, const float* __restrict__ Whh,
    const float* __restrict__ bih, const float* __restrict__ bhh,
    const float* __restrict__ Wqg, const float* __restrict__ Wm,
    const float* __restrict__ bm, const float* __restrict__ bqg,
    const float* __restrict__ Wqp, const float* __restrict__ Wrg,
    const float* __restrict__ brg, const float* __restrict__ bqp,
    float* __restrict__ WcatT, float* __restrict__ bcat,
    float* __restrict__ Wfused, float* __restrict__ bfused,
    float* __restrict__ Wgp, float* __restrict__ bgp)
{
  const int blk = blockIdx.x, t = threadIdx.x;
  if (blk == 0) {
    float acc = bqp[t];
    for (int tt = 0; tt < 256; ++tt) acc += Wqp[(t << 8) + tt] * brg[tt];
    bgp[t] = acc;
  } else if (blk <= 2048) {
    const int id = ((blk - 1) << 8) + t;      // 0..524287
    const int n = id & 1023, k = id >> 10;
    const int r = ((n & 3) << 8) + (n >> 2);
    WcatT[id] = (k < 256) ? Wih[(r << 8) + k] : Whh[(r << 8) + (k - 256)];
    if (id < 1024) {
      const int rr = ((id & 3) << 8) + (id >> 2);
      bcat[id] = bih[rr] + bhh[rr];
    }
  } else if (blk <= 2368) {
    const int id = ((blk - 2049) << 8) + t;   // 0..81919
    const int o = id / 320, j = id % 320;
    float acc = 0.f;
    for (int tt = 0; tt < 256; ++tt) acc += Wqg[(o << 8) + tt] * Wm[tt * 320 + j];
    Wfused[id] = acc;
    if (id < 256) {
      float a2 = 0.f;
      for (int tt = 0; tt < 256; ++tt) a2 += Wqg[(id << 8) + tt] * bm[tt];
      bfused[id] = a2 + bqg[id];
    }
  } else {
    const int o = blk - 2369, k = t;
    float acc = 0.f;
    for (int tt = 0; tt < 256; ++tt) acc += Wqp[(o << 8) + tt] * Wrg[(tt << 8) + k];
    Wgp[(o << 8) + k] = acc;
  }
}

// ---------------------------------------------------------------------------
// gemm256ct (unchanged from round 5): coalesced context reads, permuted stores
// ---------------------------------------------------------------------------
__device__ __forceinline__ void gemm256ct(const float* __restrict__ A,
    const float* __restrict__ W, const float* __restrict__ bias,
    float* __restrict__ C, int bx, int by, int t)
{
  __shared__ __align__(16) float As[16][68];
  __shared__ __align__(16) float Ws2[16][68];
  const int bn = bx << 6, bm = by << 6;
  const int ty = t >> 4, tx = t & 15;
  const int lr = t >> 2, lk = (t & 3) << 2;
  const int m  = bm + lr;
  const float* wrow = W + ((size_t)(bn + lr) << 8);
  float acc[4][4] = {};
  for (int k0 = 0; k0 < 256; k0 += 16) {
    const int kk = k0 + lk;
    const float4 av = *(const float4*)(A + ((size_t)m << 8) + kk);
    const float4 wv = *(const float4*)(wrow + kk);
    As[lk + 0][lr] = av.x; As[lk + 1][lr] = av.y; As[lk + 2][lr] = av.z; As[lk + 3][lr] = av.w;
    Ws2[lk + 0][lr] = wv.x; Ws2[lk + 1][lr] = wv.y; Ws2[lk + 2][lr] = wv.z; Ws2[lk + 3][lr] = wv.w;
    __syncthreads();
#pragma unroll
    for (int k = 0; k < 16; ++k) {
      const float4 a4 = *(const float4*)&As[k][ty << 2];
      const float4 w4 = *(const float4*)&Ws2[k][tx << 2];
      acc[0][0] += a4.x * w4.x; acc[0][1] += a4.x * w4.y; acc[0][2] += a4.x * w4.z; acc[0][3] += a4.x * w4.w;
      acc[1][0] += a4.y * w4.x; acc[1][1] += a4.y * w4.y; acc[1][2] += a4.y * w4.z; acc[1][3] += a4.y * w4.w;
      acc[2][0] += a4.z * w4.x; acc[2][1] += a4.z * w4.y; acc[2][2] += a4.z * w4.z; acc[2][3] += a4.z * w4.w;
      acc[3][0] += a4.w * w4.x; acc[3][1] += a4.w * w4.y; acc[3][2] += a4.w * w4.z; acc[3][3] += a4.w * w4.w;
    }
    __syncthreads();
  }
  const float4 bv = *(const float4*)(bias + bn + (tx << 2));
#pragma unroll
  for (int i = 0; i < 4; ++i) {
    const int rr = bm + (ty << 2) + i;
    const int l = rr >> 9, b = rr & 511;
    float4 o;
    o.x = acc[i][0] + bv.x; o.y = acc[i][1] + bv.y;
    o.z = acc[i][2] + bv.z; o.w = acc[i][3] + bv.w;
    *(float4*)(C + (((size_t)(b << 6) + l) << 8) + bn + (tx << 2)) = o;
  }
}

// ---------------------------------------------------------------------------
// prep2 (unchanged from round 5)
// ---------------------------------------------------------------------------
__global__ __launch_bounds__(256) void prep2_k(
    const float* __restrict__ ctxin,
    const float* __restrict__ Wrg, const float* __restrict__ brg,
    const float* __restrict__ Wrp, const float* __restrict__ brp,
    const float* __restrict__ Wgp, const float* __restrict__ bgp,
    const float* __restrict__ Wqg, const float* __restrict__ Wm,
    const float* __restrict__ Wfused, const float* __restrict__ bfused,
    const float* __restrict__ cour,
    float* __restrict__ e2g, float* __restrict__ e2p, float* __restrict__ Eg2,
    float* __restrict__ Wq1T4, float* __restrict__ qcour)
{
  const int blk = blockIdx.x, t = threadIdx.x;
  if (blk < 2048) {
    gemm256ct(ctxin, Wrg, brg, e2g, blk & 3, blk >> 2, t);
  } else if (blk < 4096) {
    const int b2 = blk - 2048;
    gemm256ct(ctxin, Wrp, brp, e2p, b2 & 3, b2 >> 2, t);
  } else if (blk < 6144) {
    const int b2 = blk - 4096;
    gemm256ct(ctxin, Wgp, bgp, Eg2, b2 & 3, b2 >> 2, t);
  } else if (blk < 6400) {
    const int o = blk - 6144;
    float acc = 0.f;
    for (int t2 = 0; t2 < 256; ++t2) acc += Wqg[(o << 8) + t2] * Wm[t2 * 320 + t];
    Wq1T4[((t >> 2) << 10) + (o << 2) + (t & 3)] = acc;
  } else {
    const int b = blk - 6400;
    __shared__ float cs[64];
    if (t < 64) cs[t] = cour[(b << 6) + t];
    __syncthreads();
    float acc = bfused[t];
#pragma unroll 8
    for (int k = 0; k < 64; ++k) acc += Wfused[t * 320 + 256 + k] * cs[k];
    qcour[(b << 8) + t] = acc;
  }
}

// ---------------------------------------------------------------------------
// Barrier-free persistent decoder, latency-overlapped version:
//  - x-part gates GEMM (K=256) at step top; h-part GEMM for the NEXT step is
//    emitted inside the attention region (h_t ready there) -> overlaps its
//    1 MB weight stream + FMAs with the attention latency chain.
//  - e2g / e2p score operands are prefetched into VGPRs one phase early.
//  - qp uses all 1024 threads (2-way l-split + LDS combine).
// ---------------------------------------------------------------------------
__global__ __launch_bounds__(1024, 4) void decoder_loop_k(
    const float* __restrict__ dec, const float* __restrict__ h0,
    const float* __restrict__ c0, const float* __restrict__ emb,
    const float* __restrict__ WcatT, const float* __restrict__ bcat,
    const float* __restrict__ e2g, const float* __restrict__ e2p,
    const float* __restrict__ Eg2, const float* __restrict__ Wq1T4,
    const float* __restrict__ qcour, const float* __restrict__ vg,
    const float* __restrict__ vp, float* __restrict__ out_logp,
    float* __restrict__ out_sel)
{
  const int t_ = threadIdx.x;
  const int b0 = blockIdx.x << 1;
  const int tk = t_ >> 8, tc = t_ & 255;        // GEMM: 4 K-chunks x 256 units
  const int wv = t_ >> 6, lane = t_ & 63;
  const int rowW = wv >> 3, lbase = (wv & 7) << 3; // score mapping

  __shared__ __align__(16) float xhs[2][512];     // [row][ x(256) | h(256) ]
  __shared__ __align__(16) float qcs[2][256];
  __shared__ __align__(16) float bcs[1024];
  __shared__ __align__(16) float vgs[256], vps[256];
  __shared__ __align__(16) float qgs[2][256], qps[2][256];
  __shared__ __align__(16) float qpp[2][2][256];  // [lhalf][row][o]
  __shared__ float us[2][64], ps[2][64];
  __shared__ __align__(16) float redX[8][256][4]; // x-part partials
  __shared__ __align__(16) float redH[8][256][4]; // h-part partials
  __shared__ unsigned long long mlds[2];
  __shared__ int selLds[2];

  // ---- init ----
  if (t_ < 512) {
    const int r = t_ >> 8, i = t_ & 255;
    xhs[r][i]       = dec[((b0 + r) << 8) + i];
    xhs[r][256 + i] = h0[((b0 + r) << 8) + i];
    qcs[r][i]       = qcour[((b0 + r) << 8) + i];
  } else if (t_ < 768) {
    vgs[t_ & 255] = vg[t_ & 255];
  } else {
    vps[t_ & 255] = vp[t_ & 255];
  }
  bcs[t_] = bcat[t_];
  float c_r0 = 0.f, c_r1 = 0.f;
  if (t_ < 256) {
    c_r0 = c0[(b0 << 8) + t_];
    c_r1 = c0[((b0 + 1) << 8) + t_];
  }
  if (t_ == 0) { mlds[0] = 0ULL; mlds[1] = 0ULL; selLds[0] = 0; selLds[1] = 0; }
  __syncthreads();

  const float* wbX = WcatT + ((size_t)(tk << 6) << 10) + (tc << 2);
  const float* wbH = WcatT + ((size_t)(256 + (tk << 6)) << 10) + (tc << 2);
  const float* xsec0 = &xhs[0][tk << 6];
  const float* xsec1 = &xhs[1][tk << 6];
  const float* hsec0 = &xhs[0][256 + (tk << 6)];
  const float* hsec1 = &xhs[1][256 + (tk << 6)];

  // ---- pre-loop: h-part partials for h0 ----
  {
    float a00 = 0.f, a01 = 0.f, a02 = 0.f, a03 = 0.f;
    float a10 = 0.f, a11 = 0.f, a12 = 0.f, a13 = 0.f;
#pragma unroll 4
    for (int kk = 0; kk < 64; kk += 2) {
      const float2 x0 = *(const float2*)(hsec0 + kk);
      const float2 x1 = *(const float2*)(hsec1 + kk);
      const float4 w0 = *(const float4*)(wbH + ((size_t)kk << 10));
      const float4 w1 = *(const float4*)(wbH + ((size_t)(kk + 1) << 10));
      a00 += w0.x * x0.x; a01 += w0.y * x0.x; a02 += w0.z * x0.x; a03 += w0.w * x0.x;
      a10 += w0.x * x1.x; a11 += w0.y * x1.x; a12 += w0.z * x1.x; a13 += w0.w * x1.x;
      a00 += w1.x * x0.y; a01 += w1.y * x0.y; a02 += w1.z * x0.y; a03 += w1.w * x0.y;
      a10 += w1.x * x1.y; a11 += w1.y * x1.y; a12 += w1.z * x1.y; a13 += w1.w * x1.y;
    }
    *(float4*)&redH[(tk << 1) | 0][tc][0] = make_float4(a00, a01, a02, a03);
    *(float4*)&redH[(tk << 1) | 1][tc][0] = make_float4(a10, a11, a12, a13);
  }

  for (int step = 0; step < 64; ++step) {
    // ---- A: prefetch e2g operands for this step's scores_g ----
    float4 eg[8];
    {
      const float* egb = e2g + ((size_t)(b0 + rowW) << 14) + (lane << 2);
#pragma unroll
      for (int li = 0; li < 8; ++li) eg[li] = *(const float4*)(egb + ((lbase + li) << 8));
    }

    // ---- B: x-part gates GEMM (K=256) ----
    {
      float a00 = 0.f, a01 = 0.f, a02 = 0.f, a03 = 0.f;
      float a10 = 0.f, a11 = 0.f, a12 = 0.f, a13 = 0.f;
#pragma unroll 4
      for (int kk = 0; kk < 64; kk += 2) {
        const float2 x0 = *(const float2*)(xsec0 + kk);
        const float2 x1 = *(const float2*)(xsec1 + kk);
        const float4 w0 = *(const float4*)(wbX + ((size_t)kk << 10));
        const float4 w1 = *(const float4*)(wbX + ((size_t)(kk + 1) << 10));
        a00 += w0.x * x0.x; a01 += w0.y * x0.x; a02 += w0.z * x0.x; a03 += w0.w * x0.x;
        a10 += w0.x * x1.x; a11 += w0.y * x1.x; a12 += w0.z * x1.x; a13 += w0.w * x1.x;
        a00 += w1.x * x0.y; a01 += w1.y * x0.y; a02 += w1.z * x0.y; a03 += w1.w * x0.y;
        a10 += w1.x * x1.y; a11 += w1.y * x1.y; a12 += w1.z * x1.y; a13 += w1.w * x1.y;
      }
      *(float4*)&redX[(tk << 1) | 0][tc][0] = make_float4(a00, a01, a02, a03);
      *(float4*)&redX[(tk << 1) | 1][tc][0] = make_float4(a10, a11, a12, a13);
    }
    __syncthreads();                                        // C

    // ---- D: LSTM epilogue (sum x-part + h-part partials) ----
    if (t_ < 256) {
      const float4 b4 = *(const float4*)&bcs[t_ << 2];
      const float4 x0 = *(const float4*)&redX[0][t_][0];
      const float4 x2 = *(const float4*)&redX[2][t_][0];
      const float4 x4 = *(const float4*)&redX[4][t_][0];
      const float4 x6 = *(const float4*)&redX[6][t_][0];
      const float4 h0v = *(const float4*)&redH[0][t_][0];
      const float4 h2 = *(const float4*)&redH[2][t_][0];
      const float4 h4 = *(const float4*)&redH[4][t_][0];
      const float4 h6 = *(const float4*)&redH[6][t_][0];
      {
        const float gi = (((x0.x + x2.x) + x4.x) + x6.x) + (((h0v.x + h2.x) + h4.x) + h6.x) + b4.x;
        const float gf = (((x0.y + x2.y) + x4.y) + x6.y) + (((h0v.y + h2.y) + h4.y) + h6.y) + b4.y;
        const float gg = (((x0.z + x2.z) + x4.z) + x6.z) + (((h0v.z + h2.z) + h4.z) + h6.z) + b4.z;
        const float go = (((x0.w + x2.w) + x4.w) + x6.w) + (((h0v.w + h2.w) + h4.w) + h6.w) + b4.w;
        c_r0 = fsigm(gf) * c_r0 + fsigm(gi) * ftanh(gg);
        xhs[0][256 + t_] = fsigm(go) * ftanh(c_r0);
      }
      const float4 y1 = *(const float4*)&redX[1][t_][0];
      const float4 y3 = *(const float4*)&redX[3][t_][0];
      const float4 y5 = *(const float4*)&redX[5][t_][0];
      const float4 y7 = *(const float4*)&redX[7][t_][0];
      const float4 g1 = *(const float4*)&redH[1][t_][0];
      const float4 g3 = *(const float4*)&redH[3][t_][0];
      const float4 g5 = *(const float4*)&redH[5][t_][0];
      const float4 g7 = *(const float4*)&redH[7][t_][0];
      {
        const float gi = (((y1.x + y3.x) + y5.x) + y7.x) + (((g1.x + g3.x) + g5.x) + g7.x) + b4.x;
        const float gf = (((y1.y + y3.y) + y5.y) + y7.y) + (((g1.y + g3.y) + g5.y) + g7.y) + b4.y;
        const float gg = (((y1.z + y3.z) + y5.z) + y7.z) + (((g1.z + g3.z) + g5.z) + g7.z) + b4.z;
        const float go = (((y1.w + y3.w) + y5.w) + y7.w) + (((g1.w + g3.w) + g5.w) + g7.w) + b4.w;
        c_r1 = fsigm(gf) * c_r1 + fsigm(gi) * ftanh(gg);
        xhs[1][256 + t_] = fsigm(go) * ftanh(c_r1);
      }
    }
    __syncthreads();                                        // E (h_t ready)

    // ---- F: h-part GEMM for NEXT step (overlaps with attention below) ----
    {
      float a00 = 0.f, a01 = 0.f, a02 = 0.f, a03 = 0.f;
      float a10 = 0.f, a11 = 0.f, a12 = 0.f, a13 = 0.f;
#pragma unroll 4
      for (int kk = 0; kk < 64; kk += 2) {
        const float2 x0 = *(const float2*)(hsec0 + kk);
        const float2 x1 = *(const float2*)(hsec1 + kk);
        const float4 w0 = *(const float4*)(wbH + ((size_t)kk << 10));
        const float4 w1 = *(const float4*)(wbH + ((size_t)(kk + 1) << 10));
        a00 += w0.x * x0.x; a01 += w0.y * x0.x; a02 += w0.z * x0.x; a03 += w0.w * x0.x;
        a10 += w0.x * x1.x; a11 += w0.y * x1.x; a12 += w0.z * x1.x; a13 += w0.w * x1.x;
        a00 += w1.x * x0.y; a01 += w1.y * x0.y; a02 += w1.z * x0.y; a03 += w1.w * x0.y;
        a10 += w1.x * x1.y; a11 += w1.y * x1.y; a12 += w1.z * x1.y; a13 += w1.w * x1.y;
      }
      *(float4*)&redH[(tk << 1) | 0][tc][0] = make_float4(a00, a01, a02, a03);
      *(float4*)&redH[(tk << 1) | 1][tc][0] = make_float4(a10, a11, a12, a13);
    }
    // ---- G: qg matvec (waves 0-3; runs concurrently with F on other waves) --
    if (t_ < 256) {
      float q0 = qcs[0][t_], q1 = qcs[1][t_];
      const float4* wp = (const float4*)Wq1T4 + t_;
#pragma unroll 8
      for (int kc = 0; kc < 64; ++kc) {
        const float4 w4  = wp[kc << 8];
        const float4 h40 = *(const float4*)&xhs[0][256 + (kc << 2)];
        const float4 h41 = *(const float4*)&xhs[1][256 + (kc << 2)];
        q0 += w4.x * h40.x + w4.y * h40.y + w4.z * h40.z + w4.w * h40.w;
        q1 += w4.x * h41.x + w4.y * h41.y + w4.z * h41.z + w4.w * h41.w;
      }
      qgs[0][t_] = q0; qgs[1][t_] = q1;
    }
    __syncthreads();                                        // H

    // ---- I: scores_g from prefetched regs ----
    {
      const float4 q4 = *(const float4*)&qgs[rowW][lane << 2];
      const float4 v4 = *(const float4*)&vgs[lane << 2];
      const unsigned long long mm = mlds[rowW];
#pragma unroll
      for (int li = 0; li < 8; ++li) {
        const int l = lbase + li;
        const float4 e4 = eg[li];
        float s = v4.x * ftanh(q4.x + e4.x) + v4.y * ftanh(q4.y + e4.y)
                + v4.z * ftanh(q4.z + e4.z) + v4.w * ftanh(q4.w + e4.w);
#pragma unroll
        for (int off = 32; off; off >>= 1) s += __shfl_xor(s, off, 64);
        if (lane == 0) us[rowW][l] = ((mm >> l) & 1ULL) ? NEGV : s;
      }
    }
    // prefetch e2p operands for scores_p (latency hidden under softmax/qp)
    float4 ep[8];
    {
      const float* epb = e2p + ((size_t)(b0 + rowW) << 14) + (lane << 2);
#pragma unroll
      for (int li = 0; li < 8; ++li) ep[li] = *(const float4*)(epb + ((lbase + li) << 8));
    }
    __syncthreads();                                        // J

    // ---- K: softmax_g ----
    if (t_ < 128) {
      const int row = t_ >> 6;
      const float xv = us[row][lane];
      float mx = xv;
#pragma unroll
      for (int off = 32; off; off >>= 1) mx = fmaxf(mx, __shfl_xor(mx, off, 64));
      const float ev = __expf(xv - mx);
      float sum = ev;
#pragma unroll
      for (int off = 32; off; off >>= 1) sum += __shfl_xor(sum, off, 64);
      ps[row][lane] = ev / sum;
    }
    __syncthreads();                                        // L

    // ---- M: qp partials (all 1024 threads; 2-way l-split) ----
    {
      const int r = t_ >> 9, lh = (t_ >> 8) & 1, o = t_ & 255;
      const float* ec = Eg2 + ((size_t)(b0 + r) << 14) + ((size_t)(lh << 5) << 8) + o;
      float aq = 0.f;
#pragma unroll 8
      for (int l = 0; l < 32; ++l) aq += ps[r][(lh << 5) + l] * ec[l << 8];
      qpp[lh][r][o] = aq;
    }
    __syncthreads();                                        // N

    // ---- O: qp combine ----
    if (t_ < 512) {
      const int r = t_ >> 8, o = t_ & 255;
      qps[r][o] = qpp[0][r][o] + qpp[1][r][o];
    }
    __syncthreads();                                        // P

    // ---- Q: scores_p from prefetched regs ----
    {
      const float4 q4 = *(const float4*)&qps[rowW][lane << 2];
      const float4 v4 = *(const float4*)&vps[lane << 2];
      const unsigned long long mm = mlds[rowW];
#pragma unroll
      for (int li = 0; li < 8; ++li) {
        const int l = lbase + li;
        const float4 e4 = ep[li];
        float s = v4.x * ftanh(q4.x + e4.x) + v4.y * ftanh(q4.y + e4.y)
                + v4.z * ftanh(q4.z + e4.z) + v4.w * ftanh(q4.w + e4.w);
#pragma unroll
        for (int off = 32; off; off >>= 1) s += __shfl_xor(s, off, 64);
        if (lane == 0) us[rowW][l] = ((mm >> l) & 1ULL) ? NEGV : 10.0f * ftanh(s);
      }
    }
    __syncthreads();                                        // R

    // ---- S: log-softmax, argmax, outputs, mask update for next step ----
    if (t_ < 128) {
      const int row = t_ >> 6;
      const float xv = us[row][lane];
      float mx = xv;
#pragma unroll
      for (int off = 32; off; off >>= 1) mx = fmaxf(mx, __shfl_xor(mx, off, 64));
      const float sh = xv - mx;
      const float ev = __expf(sh);
      float sum = ev;
#pragma unroll
      for (int off = 32; off; off >>= 1) sum += __shfl_xor(sum, off, 64);
      const float lp = sh - __logf(sum);
      out_logp[((size_t)(b0 + row) << 12) + (step << 6) + lane] = lp;
      float bv = lp; int bi = lane;
#pragma unroll
      for (int off = 32; off; off >>= 1) {
        const float ov = __shfl_xor(bv, off, 64);
        const int   oi = __shfl_xor(bi, off, 64);
        if (ov > bv || (ov == bv && oi < bi)) { bv = ov; bi = oi; }
      }
      if (lane == 0) {
        selLds[row] = bi;
        out_sel[((b0 + row) << 6) + step] = (float)bi;
        // mask update (reference applies it at start of next step; identical)
        unsigned long long m = mlds[row];
        m |= (1ULL << bi);
        if (m == ~0ULL) m &= ~(1ULL << 63);
        mlds[row] = m;
      }
    }
    __syncthreads();                                        // T

    // ---- U: embedding gather -> next x ----
    if (t_ < 512) {
      const int r = t_ >> 8, o = t_ & 255;
      xhs[r][o] = emb[(((size_t)(selLds[r] << 9) + b0 + r) << 8) + o];
    }
    __syncthreads();                                        // V
  }
}

// ---------------------------------------------------------------------------
extern "C" void kernel_launch(void* const* d_in, const int* in_sizes, int n_in,
                              void* d_out, int out_size, void* d_ws, size_t ws_size,
                              hipStream_t stream)
{
  const float* dec   = (const float*)d_in[0];
  const float* emb   = (const float*)d_in[1];
  const float* h0    = (const float*)d_in[2];
  const float* c0    = (const float*)d_in[3];
  const float* ctxin = (const float*)d_in[4];
  const float* cour  = (const float*)d_in[5];
  const float* Wih   = (const float*)d_in[7];
  const float* Whh   = (const float*)d_in[8];
  const float* bih   = (const float*)d_in[9];
  const float* bhh   = (const float*)d_in[10];
  const float* Wm    = (const float*)d_in[11];
  const float* bm    = (const float*)d_in[12];
  const float* Wqp   = (const float*)d_in[13];
  const float* bqp   = (const float*)d_in[14];
  const float* Wrp   = (const float*)d_in[15];
  const float* brp   = (const float*)d_in[16];
  const float* vp    = (const float*)d_in[17];
  const float* Wqg   = (const float*)d_in[18];
  const float* bqg   = (const float*)d_in[19];
  const float* Wrg   = (const float*)d_in[20];
  const float* brg   = (const float*)d_in[21];
  const float* vg    = (const float*)d_in[22];

  float* ws = (float*)d_ws;
  float* e2g    = ws + 0;         // [B][L][H] 8388608
  float* e2p    = ws + 8388608;   // 8388608
  float* Eg2    = ws + 16777216;  // 8388608
  float* WcatT  = ws + 25165824;  // [K=512][N=1024] 524288
  float* bcat   = ws + 25690112;  // 1024
  float* Wfused = ws + 25691136;  // 81920
  float* bfused = ws + 25773056;  // 256
  float* Wq1T4  = ws + 25773312;  // 65536
  float* qcour  = ws + 25838848;  // 131072
  float* Wgp    = ws + 25969920;  // 65536
  float* bgp    = ws + 26035456;  // 256

  float* out_logp = (float*)d_out;            // [B][64][64]
  float* out_sel  = (float*)d_out + 2097152;  // [B][64]

  prep1_k<<<2625, 256, 0, stream>>>(Wih, Whh, bih, bhh, Wqg, Wm, bm, bqg,
                                    Wqp, Wrg, brg, bqp,
                                    WcatT, bcat, Wfused, bfused, Wgp, bgp);
  prep2_k<<<6912, 256, 0, stream>>>(ctxin, Wrg, brg, Wrp, brp, Wgp, bgp,
                                    Wqg, Wm, Wfused, bfused, cour,
                                    e2g, e2p, Eg2, Wq1T4, qcour);
  decoder_loop_k<<<256, 1024, 0, stream>>>(dec, h0, c0, emb, WcatT, bcat,
                                           e2g, e2p, Eg2, Wq1T4, qcour,
                                           vg, vp, out_logp, out_sel);
}